// Round 6
// baseline (32851.761 us; speedup 1.0000x reference)
//
#include <hip/hip_runtime.h>
#include <hip/hip_bf16.h>

#define B_SZ   256
#define T_SZ   256
#define FUT    32
#define TF_SZ  (T_SZ + FUT)
#define HIDN   1024
#define INDIM  64
#define OUTDIM 64
#define NBLK   256

typedef __attribute__((ext_vector_type(8))) short bf16x8;
typedef __attribute__((ext_vector_type(4))) float f32x4;

__device__ __forceinline__ float bf2f(unsigned short u) {
    union { unsigned int i; float f; } v; v.i = (unsigned int)u << 16; return v.f;
}
__device__ __forceinline__ unsigned short f2bf(float f) {
    union { float f; unsigned int i; } v; v.f = f;
    unsigned int r = v.i + 0x7FFFu + ((v.i >> 16) & 1u);
    return (unsigned short)(r >> 16);
}
__device__ __forceinline__ float sigm(float x) { return 1.0f / (1.0f + __expf(-x)); }

// Lightweight device-scope grid barrier (sense-reversing, sleep backoff).
__device__ __forceinline__ void grid_barrier(unsigned int* bar) {
    __syncthreads();
    if (threadIdx.x == 0) {
        __builtin_amdgcn_fence(__ATOMIC_RELEASE, "agent");
        unsigned int gen = __hip_atomic_load(&bar[1], __ATOMIC_ACQUIRE,
                                             __HIP_MEMORY_SCOPE_AGENT);
        unsigned int a = __hip_atomic_fetch_add(&bar[0], 1u, __ATOMIC_RELAXED,
                                                __HIP_MEMORY_SCOPE_AGENT);
        if (a == NBLK - 1) {
            __hip_atomic_store(&bar[0], 0u, __ATOMIC_RELAXED,
                               __HIP_MEMORY_SCOPE_AGENT);
            __hip_atomic_store(&bar[1], gen + 1u, __ATOMIC_RELEASE,
                               __HIP_MEMORY_SCOPE_AGENT);
        } else {
            while (__hip_atomic_load(&bar[1], __ATOMIC_RELAXED,
                                     __HIP_MEMORY_SCOPE_AGENT) == gen)
                __builtin_amdgcn_s_sleep(2);
        }
        __builtin_amdgcn_fence(__ATOMIC_ACQUIRE, "agent");
    }
    __syncthreads();
}

// ---------------------------------------------------------------------------
// Persistent 2-layer LSTM, spill-proof partition.
// 256 blocks x 512 threads (1 block/CU). Block bg owns hidden units
// [bg*4, bg*4+4) x 4 gates = 16 gate-rows (ONE MFMA A-fragment), ALL 256
// batch rows. Wave ks = K-slice. Weights: w2r 32 + w1r 20 = 52 VGPRs/thread;
// transient B-frags 32; total live ~115 < 128 -> no spill under any cap.
// ---------------------------------------------------------------------------
__global__ __attribute__((amdgpu_flat_work_group_size(512, 512),
                          amdgpu_waves_per_eu(2, 2)))
void lstm_persist(
    const unsigned short* __restrict__ xbf,    // [256][256][64]
    unsigned short* __restrict__ xfut,         // [256][64]
    const unsigned short* __restrict__ W1,     // [4096][1088]
    const unsigned short* __restrict__ W2,     // [4096][2048]
    const unsigned short* __restrict__ Wlin,   // [64][1024]
    const unsigned short* __restrict__ Wo2i,   // [64][64]
    const float* __restrict__ b_ih1, const float* __restrict__ b_hh1,
    const float* __restrict__ b_ih2, const float* __restrict__ b_hh2,
    const float* __restrict__ blin, const float* __restrict__ bo2i,
    unsigned short* __restrict__ hh0,          // [256][2048] = [h1|h2]
    unsigned short* __restrict__ hh1,
    float* __restrict__ outp,                  // [256][288][64] f32
    unsigned int* __restrict__ bar)
{
    __shared__ float part[8][16][258];   // [kslice][gate-row16][batch256+pad]
    __shared__ float red[512];
    __shared__ float blds[32];           // [layer2][gate4][unit4]

    const int tid  = threadIdx.x;
    const int bg   = blockIdx.x;         // 0..255: unit group (4 units)
    const int ks   = tid >> 6;
    const int lane = tid & 63;
    const int am   = lane & 15, ah = lane >> 4;

    if (tid < 32) {
        const int L = tid >> 4, G = (tid >> 2) & 3, q = tid & 3;
        const int j = bg * 4 + q;
        blds[tid] = L ? (b_ih2[G * HIDN + j] + b_hh2[G * HIDN + j])
                      : (b_ih1[G * HIDN + j] + b_hh1[G * HIDN + j]);
    }

    // A-fragment row am -> W row: gate g = am>>2, unit q = am&3
    const int wr = (am >> 2) * 1024 + bg * 4 + (am & 3);

    // ---- register-resident W (loaded once): 52 VGPRs ----
    bf16x8 w2r[8];
    {
        const size_t b0 = (size_t)wr * 2048 + ks * 256 + ah * 8;
#pragma unroll
        for (int kk = 0; kk < 8; ++kk)
            w2r[kk] = *(const bf16x8*)(W2 + b0 + kk * 32);
    }
    const int kb1 = (ks < 2) ? ks * 160 : 320 + (ks - 2) * 128;
    const int kc1 = (ks < 2) ? 5 : 4;
    bf16x8 w1r[5];
#pragma unroll
    for (int kk = 0; kk < 5; ++kk) w1r[kk] = (bf16x8){0,0,0,0,0,0,0,0};
    {
        const size_t b0 = (size_t)wr * 1088 + kb1 + ah * 8;
#pragma unroll
        for (int kk = 0; kk < 5; ++kk) if (kk < kc1)
            w1r[kk] = *(const bf16x8*)(W1 + b0 + kk * 32);
    }

    // epilogue: thread handles cells (jqA, bl) and (jqA+2, bl)
    const int jqA = tid >> 8;            // 0..1
    const int bl  = tid & 255;
    float c1a = 0.f, c1b = 0.f, c2a = 0.f, c2b = 0.f;

    // fold constants
    const int fc = bg & 63, fq = bg >> 6;
    const int frow = tid & 63, fkq = tid >> 6;
    __syncthreads();

    for (int t = 0; t < TF_SZ; ++t) {
        const unsigned short* hsrc = (t & 1) ? hh1 : hh0;
        unsigned short*       hdst = (t & 1) ? hh0 : hh1;
        const unsigned short* xsrc = (t < T_SZ) ? (xbf + (size_t)t * B_SZ * INDIM) : xfut;

        // ===== phase 1: fold out(t-1), then layer-1 gates + cell =====
        if (t >= 1 && t <= 255) {
            const unsigned short* hp = hsrc + (size_t)(fq * 64 + frow) * 2048 + 1024 + fkq * 128;
            const unsigned short* wp = Wlin + (size_t)fc * 1024 + fkq * 128;
            float p = 0.f;
#pragma unroll
            for (int k = 0; k < 128; k += 8) {
                bf16x8 hv = *(const bf16x8*)(hp + k);
                bf16x8 wv = *(const bf16x8*)(wp + k);
#pragma unroll
                for (int u = 0; u < 8; ++u)
                    p += bf2f((unsigned short)hv[u]) * bf2f((unsigned short)wv[u]);
            }
            red[fkq * 64 + frow] = p;
            __syncthreads();
            if (tid < 64) {
                float s = blin[fc];
#pragma unroll
                for (int u = 0; u < 8; ++u) s += red[u * 64 + tid];
                outp[((size_t)(fq * 64 + tid) * TF_SZ + (t - 1)) * OUTDIM + fc] = s;
            }
            __syncthreads();
        }

        // layer-1 gates: one 16-row batch fragment at a time
#pragma unroll 1
        for (int np = 0; np < 16; ++np) {
            const int brow = np * 16 + am;
            bf16x8 f[5];
#pragma unroll
            for (int kk = 0; kk < 5; ++kk) if (kk < kc1) {
                const int k = kb1 + kk * 32 + ah * 8;
                f[kk] = (k < 64)
                    ? *(const bf16x8*)(xsrc + (size_t)brow * INDIM + k)
                    : *(const bf16x8*)(hsrc + (size_t)brow * 2048 + (k - 64));
            }
            f32x4 pe = {0,0,0,0}, po = {0,0,0,0};
#pragma unroll
            for (int kk = 0; kk < 5; ++kk) if (kk < kc1) {
                if (kk & 1) po = __builtin_amdgcn_mfma_f32_16x16x32_bf16(w1r[kk], f[kk], po, 0, 0, 0);
                else        pe = __builtin_amdgcn_mfma_f32_16x16x32_bf16(w1r[kk], f[kk], pe, 0, 0, 0);
            }
#pragma unroll
            for (int r = 0; r < 4; ++r)
                part[ks][ah * 4 + r][np * 16 + am] = pe[r] + po[r];
        }
        __syncthreads();
        {   // layer-1 cell, unit jqA
            float g0 = 0.f, g1 = 0.f, g2 = 0.f, g3 = 0.f;
#pragma unroll
            for (int s = 0; s < 8; ++s) {
                g0 += part[s][jqA][bl];      g1 += part[s][4 + jqA][bl];
                g2 += part[s][8 + jqA][bl];  g3 += part[s][12 + jqA][bl];
            }
            const float gi = sigm(g0 + blds[jqA]),      gf = sigm(g1 + blds[4 + jqA]);
            const float gg = tanhf(g2 + blds[8 + jqA]), go = sigm(g3 + blds[12 + jqA]);
            c1a = gf * c1a + gi * gg;
            hdst[(size_t)bl * 2048 + bg * 4 + jqA] = f2bf(go * tanhf(c1a));
        }
        {   // layer-1 cell, unit jqA+2
            const int jq = jqA + 2;
            float g0 = 0.f, g1 = 0.f, g2 = 0.f, g3 = 0.f;
#pragma unroll
            for (int s = 0; s < 8; ++s) {
                g0 += part[s][jq][bl];      g1 += part[s][4 + jq][bl];
                g2 += part[s][8 + jq][bl];  g3 += part[s][12 + jq][bl];
            }
            const float gi = sigm(g0 + blds[jq]),      gf = sigm(g1 + blds[4 + jq]);
            const float gg = tanhf(g2 + blds[8 + jq]), go = sigm(g3 + blds[12 + jq]);
            c1b = gf * c1b + gi * gg;
            hdst[(size_t)bl * 2048 + bg * 4 + jq] = f2bf(go * tanhf(c1b));
        }
        grid_barrier(bar);

        // ===== phase 2: layer-2 gates + cell =====
        {
            const unsigned short* hb = (ks < 4) ? hdst : hsrc;   // h1(t) | h2(t-1)
#pragma unroll 1
            for (int np = 0; np < 16; ++np) {
                const int brow = np * 16 + am;
                const unsigned short* bp = hb + (size_t)brow * 2048 + ks * 256 + ah * 8;
                bf16x8 f[8];
#pragma unroll
                for (int kk = 0; kk < 8; ++kk)
                    f[kk] = *(const bf16x8*)(bp + kk * 32);
                f32x4 pe = {0,0,0,0}, po = {0,0,0,0};
#pragma unroll
                for (int kk = 0; kk < 8; ++kk) {
                    if (kk & 1) po = __builtin_amdgcn_mfma_f32_16x16x32_bf16(w2r[kk], f[kk], po, 0, 0, 0);
                    else        pe = __builtin_amdgcn_mfma_f32_16x16x32_bf16(w2r[kk], f[kk], pe, 0, 0, 0);
                }
#pragma unroll
                for (int r = 0; r < 4; ++r)
                    part[ks][ah * 4 + r][np * 16 + am] = pe[r] + po[r];
            }
        }
        __syncthreads();
        {   // layer-2 cell, unit jqA
            float g0 = 0.f, g1 = 0.f, g2 = 0.f, g3 = 0.f;
#pragma unroll
            for (int s = 0; s < 8; ++s) {
                g0 += part[s][jqA][bl];      g1 += part[s][4 + jqA][bl];
                g2 += part[s][8 + jqA][bl];  g3 += part[s][12 + jqA][bl];
            }
            const float gi = sigm(g0 + blds[16 + jqA]),      gf = sigm(g1 + blds[20 + jqA]);
            const float gg = tanhf(g2 + blds[24 + jqA]), go = sigm(g3 + blds[28 + jqA]);
            c2a = gf * c2a + gi * gg;
            hdst[(size_t)bl * 2048 + 1024 + bg * 4 + jqA] = f2bf(go * tanhf(c2a));
        }
        {   // layer-2 cell, unit jqA+2
            const int jq = jqA + 2;
            float g0 = 0.f, g1 = 0.f, g2 = 0.f, g3 = 0.f;
#pragma unroll
            for (int s = 0; s < 8; ++s) {
                g0 += part[s][jq][bl];      g1 += part[s][4 + jq][bl];
                g2 += part[s][8 + jq][bl];  g3 += part[s][12 + jq][bl];
            }
            const float gi = sigm(g0 + blds[16 + jq]),      gf = sigm(g1 + blds[20 + jq]);
            const float gg = tanhf(g2 + blds[24 + jq]), go = sigm(g3 + blds[28 + jq]);
            c2b = gf * c2b + gi * gg;
            hdst[(size_t)bl * 2048 + 1024 + bg * 4 + jq] = f2bf(go * tanhf(c2b));
        }
        grid_barrier(bar);

        // ===== phase 3 (t>=255): out(t) + feedback x(t+1) =====
        if (t >= T_SZ - 1) {
            if (bg < 32) {
                unsigned short* h2s = (unsigned short*)&part[0][0][0];  // [8][1024]
                const int rowbase = bg * 8;
                for (int i = tid; i < 1024; i += 512) {
                    const int rr = i >> 7, k8 = (i & 127) * 8;
                    *(bf16x8*)&h2s[rr * 1024 + k8] =
                        *(const bf16x8*)&hdst[(size_t)(rowbase + rr) * 2048 + 1024 + k8];
                }
                __syncthreads();
                const int rl = tid >> 6, col = tid & 63;
                float acc = blin[col];
                const unsigned short* wl = Wlin + (size_t)col * HIDN;
                for (int k = 0; k < HIDN; k += 8) {
                    bf16x8 hv = *(const bf16x8*)&h2s[rl * 1024 + k];
                    bf16x8 wv = *(const bf16x8*)&wl[k];
#pragma unroll
                    for (int u = 0; u < 8; ++u)
                        acc += bf2f((unsigned short)hv[u]) * bf2f((unsigned short)wv[u]);
                }
                outp[((size_t)(rowbase + rl) * TF_SZ + t) * OUTDIM + col] = acc;
                if (t < TF_SZ - 1) {
                    red[rl * 64 + col] = acc;
                    __syncthreads();
                    float x = bo2i[col];
                    const unsigned short* w2 = Wo2i + (size_t)col * OUTDIM;
#pragma unroll 8
                    for (int jj = 0; jj < OUTDIM; ++jj)
                        x += red[rl * 64 + jj] * bf2f(w2[jj]);
                    xfut[(size_t)(rowbase + rl) * INDIM + col] = f2bf(x);
                }
            }
            grid_barrier(bar);
        }
    }
}

__global__ void conv_strided(const float* __restrict__ src,
                             unsigned short* __restrict__ dst,
                             int cols, int dstride, int doff, int total)
{
    const int idx = blockIdx.x * 256 + threadIdx.x;
    if (idx >= total) return;
    const int r = idx / cols, c = idx - r * cols;
    dst[(size_t)r * dstride + doff + c] = f2bf(src[idx]);
}

__global__ void conv_x(const float* __restrict__ src,
                       unsigned short* __restrict__ dst)
{
    const int idx = blockIdx.x * 256 + threadIdx.x;
    const int f = idx & 63, t = (idx >> 6) & 255, b = idx >> 14;
    dst[((size_t)t * B_SZ + b) * INDIM + f] = f2bf(src[idx]);
}

extern "C" void kernel_launch(void* const* d_in, const int* in_sizes, int n_in,
                              void* d_out, int out_size, void* d_ws, size_t ws_size,
                              hipStream_t stream)
{
    const float* input = (const float*)d_in[0];
    const float* W_ih1 = (const float*)d_in[1];
    const float* W_hh1 = (const float*)d_in[2];
    const float* b_ih1 = (const float*)d_in[3];
    const float* b_hh1 = (const float*)d_in[4];
    const float* W_ih2 = (const float*)d_in[5];
    const float* W_hh2 = (const float*)d_in[6];
    const float* b_ih2 = (const float*)d_in[7];
    const float* b_hh2 = (const float*)d_in[8];
    const float* W_lin = (const float*)d_in[9];
    const float* b_lin = (const float*)d_in[10];
    const float* W_o2i = (const float*)d_in[11];
    const float* b_o2i = (const float*)d_in[12];
    float* outp = (float*)d_out;

    char* ws = (char*)d_ws;
    unsigned short* Wcat1 = (unsigned short*)ws; ws += (size_t)4096 * 1088 * 2;
    unsigned short* Wcat2 = (unsigned short*)ws; ws += (size_t)4096 * 2048 * 2;
    unsigned short* Wlinb = (unsigned short*)ws; ws += (size_t)64 * 1024 * 2;
    unsigned short* Wo2ib = (unsigned short*)ws; ws += (size_t)64 * 64 * 2;
    unsigned short* xbf   = (unsigned short*)ws; ws += (size_t)T_SZ * B_SZ * INDIM * 2;
    unsigned short* hh0   = (unsigned short*)ws; ws += (size_t)B_SZ * 2 * HIDN * 2;
    unsigned short* hh1   = (unsigned short*)ws; ws += (size_t)B_SZ * 2 * HIDN * 2;
    unsigned short* xfut  = (unsigned short*)ws; ws += (size_t)B_SZ * INDIM * 2;
    ws = (char*)(((size_t)ws + 127) & ~(size_t)127);
    unsigned int*   bar   = (unsigned int*)ws;   ws += 128;

    conv_strided<<<(4096 * 64 + 255) / 256, 256, 0, stream>>>(W_ih1, Wcat1, 64, 1088, 0, 4096 * 64);
    conv_strided<<<(4096 * 1024 + 255) / 256, 256, 0, stream>>>(W_hh1, Wcat1, 1024, 1088, 64, 4096 * 1024);
    conv_strided<<<(4096 * 1024 + 255) / 256, 256, 0, stream>>>(W_ih2, Wcat2, 1024, 2048, 0, 4096 * 1024);
    conv_strided<<<(4096 * 1024 + 255) / 256, 256, 0, stream>>>(W_hh2, Wcat2, 1024, 2048, 1024, 4096 * 1024);
    conv_strided<<<(64 * 1024 + 255) / 256, 256, 0, stream>>>(W_lin, Wlinb, 1024, 1024, 0, 64 * 1024);
    conv_strided<<<(64 * 64 + 255) / 256, 256, 0, stream>>>(W_o2i, Wo2ib, 64, 64, 0, 64 * 64);
    conv_x<<<(T_SZ * B_SZ * INDIM) / 256, 256, 0, stream>>>(input, xbf);

    hipMemsetAsync(hh0, 0, (size_t)B_SZ * 2 * HIDN * 2, stream);
    hipMemsetAsync(bar, 0, 128, stream);

    void* kargs[] = {
        (void*)&xbf, (void*)&xfut, (void*)&Wcat1, (void*)&Wcat2,
        (void*)&Wlinb, (void*)&Wo2ib,
        (void*)&b_ih1, (void*)&b_hh1, (void*)&b_ih2, (void*)&b_hh2,
        (void*)&b_lin, (void*)&b_o2i,
        (void*)&hh0, (void*)&hh1, (void*)&outp, (void*)&bar
    };
    hipLaunchCooperativeKernel((void*)lstm_persist, dim3(NBLK), dim3(512),
                               kargs, 0, stream);
}

// Round 7
// 24709.341 us; speedup vs baseline: 1.3295x; 1.3295x over previous
//
#include <hip/hip_runtime.h>
#include <hip/hip_bf16.h>

#define B_SZ   256
#define T_SZ   256
#define FUT    32
#define TF_SZ  (T_SZ + FUT)
#define HIDN   1024
#define INDIM  64
#define OUTDIM 64
#define NBLK   256
// s_getreg encoding: id=20 (HW_REG_XCC_ID), offset=0, size=32 -> (31<<11)|20
#define HWREG_XCC ((31u << 11) | 20u)

typedef __attribute__((ext_vector_type(8))) short bf16x8;
typedef __attribute__((ext_vector_type(4))) float f32x4;

__device__ __forceinline__ float bf2f(unsigned short u) {
    union { unsigned int i; float f; } v; v.i = (unsigned int)u << 16; return v.f;
}
__device__ __forceinline__ unsigned short f2bf(float f) {
    union { float f; unsigned int i; } v; v.f = f;
    unsigned int r = v.i + 0x7FFFu + ((v.i >> 16) & 1u);
    return (unsigned short)(r >> 16);
}
__device__ __forceinline__ float sigm(float x) { return 1.0f / (1.0f + __expf(-x)); }

// ---------------------------------------------------------------------------
// Grid barrier with ELECTED L2-invalidate (one per XCD per barrier).
// bar[0]=cnt, bar[1]=gen (monotone = bidx), bar[8+x]=claim, bar[24+x]=done.
// Every block: release fence (flush own dirty L2 lines) + arrive.
// After release: CAS-elected doer per XCC bucket runs the agent acquire fence
// (whole-L2 inv) ONCE; members wait on done then proceed (L2 now fresh+warm).
// Deadlock-free for arbitrary bucket sizes.
// ---------------------------------------------------------------------------
__device__ __forceinline__ void gbarrier(unsigned int* bar, unsigned int bidx) {
    __syncthreads();
    if (threadIdx.x == 0) {
        __builtin_amdgcn_fence(__ATOMIC_RELEASE, "agent");   // wb dirty L2 + waitcnt
        unsigned int a = __hip_atomic_fetch_add(&bar[0], 1u, __ATOMIC_RELAXED,
                                                __HIP_MEMORY_SCOPE_AGENT);
        if (a == NBLK - 1u) {
            __hip_atomic_store(&bar[0], 0u, __ATOMIC_RELAXED, __HIP_MEMORY_SCOPE_AGENT);
            __hip_atomic_store(&bar[1], bidx, __ATOMIC_RELEASE, __HIP_MEMORY_SCOPE_AGENT);
        } else {
            while (__hip_atomic_load(&bar[1], __ATOMIC_RELAXED,
                                     __HIP_MEMORY_SCOPE_AGENT) < bidx)
                __builtin_amdgcn_s_sleep(2);
        }
        const unsigned int xcc = __builtin_amdgcn_s_getreg(HWREG_XCC) & 15u;
        unsigned int expected = bidx - 1u;
        if (__hip_atomic_compare_exchange_strong(&bar[8 + xcc], &expected, bidx,
                __ATOMIC_RELAXED, __ATOMIC_RELAXED, __HIP_MEMORY_SCOPE_AGENT)) {
            __builtin_amdgcn_fence(__ATOMIC_ACQUIRE, "agent");   // L2 inv (once/XCD)
            __hip_atomic_store(&bar[24 + xcc], bidx, __ATOMIC_RELEASE,
                               __HIP_MEMORY_SCOPE_AGENT);
        } else {
            while (__hip_atomic_load(&bar[24 + xcc], __ATOMIC_RELAXED,
                                     __HIP_MEMORY_SCOPE_AGENT) < bidx)
                __builtin_amdgcn_s_sleep(1);
            __builtin_amdgcn_fence(__ATOMIC_ACQUIRE, "workgroup"); // order only
        }
    }
    __syncthreads();
}

// ---------------------------------------------------------------------------
// Persistent 2-layer LSTM, merged superphase schedule:
//   prologue: L1(0)                                   -> 1 barrier
//   S_t (t=0..254): {fold out(t-1) | L2(t) | L1(t+1)} -> 1 barrier/step
//   tail (t=255..287): L2(t) | out(t)+xfut | L1(t+1)  -> 3 barriers/step
// Block owns 4 hidden units x 4 gates (one A-fragment), all 256 batch rows;
// unit groups remapped so each XCD owns a contiguous 256B column band of h.
// Weights register-resident (52 VGPR). Cell state in registers.
// ---------------------------------------------------------------------------
__global__ __attribute__((amdgpu_flat_work_group_size(512, 512),
                          amdgpu_waves_per_eu(2, 2)))
void lstm_persist(
    const unsigned short* __restrict__ xbf,    // [256][256][64]
    unsigned short* __restrict__ xfut,         // [256][64]
    const unsigned short* __restrict__ W1,     // [4096][1088]
    const unsigned short* __restrict__ W2,     // [4096][2048]
    const unsigned short* __restrict__ Wlin,   // [64][1024]
    const unsigned short* __restrict__ Wo2i,   // [64][64]
    const float* __restrict__ b_ih1, const float* __restrict__ b_hh1,
    const float* __restrict__ b_ih2, const float* __restrict__ b_hh2,
    const float* __restrict__ blin, const float* __restrict__ bo2i,
    unsigned short* __restrict__ hh0,          // [256][2048] = [h1|h2]
    unsigned short* __restrict__ hh1,
    float* __restrict__ outp,                  // [256][288][64] f32
    unsigned int* __restrict__ bar)
{
    __shared__ float part[8][16][258];
    __shared__ float red[512];
    __shared__ float blds[32];

    const int tid  = threadIdx.x;
    const int id   = blockIdx.x;
    const int ug   = (id & 7) * 32 + (id >> 3);   // XCD-contiguous unit group
    const int jb   = ug * 4;                      // first of 4 hidden units
    const int ks   = tid >> 6;
    const int lane = tid & 63;
    const int am   = lane & 15, ah = lane >> 4;

    if (tid < 32) {
        const int L = tid >> 4, G = (tid >> 2) & 3, q = tid & 3;
        const int j = jb + q;
        blds[tid] = L ? (b_ih2[G * HIDN + j] + b_hh2[G * HIDN + j])
                      : (b_ih1[G * HIDN + j] + b_hh1[G * HIDN + j]);
    }

    // A-fragment row am -> W row: gate = am>>2, unit = am&3
    const int wr = (am >> 2) * 1024 + jb + (am & 3);

    bf16x8 w2r[8];
    {
        const size_t b0 = (size_t)wr * 2048 + ks * 256 + ah * 8;
#pragma unroll
        for (int kk = 0; kk < 8; ++kk)
            w2r[kk] = *(const bf16x8*)(W2 + b0 + kk * 32);
    }
    const int kb1 = (ks < 2) ? ks * 160 : 320 + (ks - 2) * 128;
    const int kc1 = (ks < 2) ? 5 : 4;
    bf16x8 w1r[5];
#pragma unroll
    for (int kk = 0; kk < 5; ++kk) w1r[kk] = (bf16x8){0,0,0,0,0,0,0,0};
    {
        const size_t b0 = (size_t)wr * 1088 + kb1 + ah * 8;
#pragma unroll
        for (int kk = 0; kk < 5; ++kk) if (kk < kc1)
            w1r[kk] = *(const bf16x8*)(W1 + b0 + kk * 32);
    }

    const int jqA = tid >> 8;          // 0..1 (units jqA and jqA+2)
    const int bl  = tid & 255;         // batch row
    float c1a = 0.f, c1b = 0.f, c2a = 0.f, c2b = 0.f;

    const int fc = id & 63, fq = id >> 6;
    const int frow = tid & 63, fkq = tid >> 6;
    __syncthreads();

    unsigned int bidx = 0;

    // ---- layer-1 GEMM + cell -> hdst cols [0,1024) ----
    auto l1_phase = [&](const unsigned short* xsrc, const unsigned short* hsrc,
                        unsigned short* hdst) {
#pragma unroll 1
        for (int np = 0; np < 16; ++np) {
            const int brow = np * 16 + am;
            bf16x8 f[5];
#pragma unroll
            for (int kk = 0; kk < 5; ++kk) if (kk < kc1) {
                const int k = kb1 + kk * 32 + ah * 8;
                f[kk] = (k < 64)
                    ? *(const bf16x8*)(xsrc + (size_t)brow * INDIM + k)
                    : *(const bf16x8*)(hsrc + (size_t)brow * 2048 + (k - 64));
            }
            f32x4 pe = {0,0,0,0}, po = {0,0,0,0};
#pragma unroll
            for (int kk = 0; kk < 5; ++kk) if (kk < kc1) {
                if (kk & 1) po = __builtin_amdgcn_mfma_f32_16x16x32_bf16(w1r[kk], f[kk], po, 0, 0, 0);
                else        pe = __builtin_amdgcn_mfma_f32_16x16x32_bf16(w1r[kk], f[kk], pe, 0, 0, 0);
            }
#pragma unroll
            for (int r = 0; r < 4; ++r)
                part[ks][ah * 4 + r][np * 16 + am] = pe[r] + po[r];
        }
        __syncthreads();
        {
            float g0 = 0.f, g1 = 0.f, g2 = 0.f, g3 = 0.f;
#pragma unroll
            for (int s = 0; s < 8; ++s) {
                g0 += part[s][jqA][bl];      g1 += part[s][4 + jqA][bl];
                g2 += part[s][8 + jqA][bl];  g3 += part[s][12 + jqA][bl];
            }
            const float gi = sigm(g0 + blds[jqA]),      gf = sigm(g1 + blds[4 + jqA]);
            const float gg = tanhf(g2 + blds[8 + jqA]), go = sigm(g3 + blds[12 + jqA]);
            c1a = gf * c1a + gi * gg;
            hdst[(size_t)bl * 2048 + jb + jqA] = f2bf(go * tanhf(c1a));
        }
        {
            const int jq = jqA + 2;
            float g0 = 0.f, g1 = 0.f, g2 = 0.f, g3 = 0.f;
#pragma unroll
            for (int s = 0; s < 8; ++s) {
                g0 += part[s][jq][bl];      g1 += part[s][4 + jq][bl];
                g2 += part[s][8 + jq][bl];  g3 += part[s][12 + jq][bl];
            }
            const float gi = sigm(g0 + blds[jq]),      gf = sigm(g1 + blds[4 + jq]);
            const float gg = tanhf(g2 + blds[8 + jq]), go = sigm(g3 + blds[12 + jq]);
            c1b = gf * c1b + gi * gg;
            hdst[(size_t)bl * 2048 + jb + jq] = f2bf(go * tanhf(c1b));
        }
        __syncthreads();   // part consumed; safe for next phase to overwrite
    };

    // ---- layer-2 GEMM + cell -> hdst cols [1024,2048). B = hsrc[0..2048) ----
    auto l2_phase = [&](const unsigned short* hsrc, unsigned short* hdst) {
#pragma unroll 1
        for (int np = 0; np < 16; ++np) {
            const int brow = np * 16 + am;
            const unsigned short* bp = hsrc + (size_t)brow * 2048 + ks * 256 + ah * 8;
            bf16x8 f[8];
#pragma unroll
            for (int kk = 0; kk < 8; ++kk)
                f[kk] = *(const bf16x8*)(bp + kk * 32);
            f32x4 pe = {0,0,0,0}, po = {0,0,0,0};
#pragma unroll
            for (int kk = 0; kk < 8; ++kk) {
                if (kk & 1) po = __builtin_amdgcn_mfma_f32_16x16x32_bf16(w2r[kk], f[kk], po, 0, 0, 0);
                else        pe = __builtin_amdgcn_mfma_f32_16x16x32_bf16(w2r[kk], f[kk], pe, 0, 0, 0);
            }
#pragma unroll
            for (int r = 0; r < 4; ++r)
                part[ks][ah * 4 + r][np * 16 + am] = pe[r] + po[r];
        }
        __syncthreads();
        {
            float g0 = 0.f, g1 = 0.f, g2 = 0.f, g3 = 0.f;
#pragma unroll
            for (int s = 0; s < 8; ++s) {
                g0 += part[s][jqA][bl];      g1 += part[s][4 + jqA][bl];
                g2 += part[s][8 + jqA][bl];  g3 += part[s][12 + jqA][bl];
            }
            const float gi = sigm(g0 + blds[16 + jqA]),      gf = sigm(g1 + blds[20 + jqA]);
            const float gg = tanhf(g2 + blds[24 + jqA]), go = sigm(g3 + blds[28 + jqA]);
            c2a = gf * c2a + gi * gg;
            hdst[(size_t)bl * 2048 + 1024 + jb + jqA] = f2bf(go * tanhf(c2a));
        }
        {
            const int jq = jqA + 2;
            float g0 = 0.f, g1 = 0.f, g2 = 0.f, g3 = 0.f;
#pragma unroll
            for (int s = 0; s < 8; ++s) {
                g0 += part[s][jq][bl];      g1 += part[s][4 + jq][bl];
                g2 += part[s][8 + jq][bl];  g3 += part[s][12 + jq][bl];
            }
            const float gi = sigm(g0 + blds[16 + jq]),      gf = sigm(g1 + blds[20 + jq]);
            const float gg = tanhf(g2 + blds[24 + jq]), go = sigm(g3 + blds[28 + jq]);
            c2b = gf * c2b + gi * gg;
            hdst[(size_t)bl * 2048 + 1024 + jb + jq] = f2bf(go * tanhf(c2b));
        }
        __syncthreads();
    };

    // ---- fold: out(tm1) = h2(tm1) @ Wlin^T + blin (1 col/block) ----
    auto fold = [&](int tm1, const unsigned short* hsrc) {
        const unsigned short* hp = hsrc + (size_t)(fq * 64 + frow) * 2048 + 1024 + fkq * 128;
        const unsigned short* wp = Wlin + (size_t)fc * 1024 + fkq * 128;
        float p = 0.f;
#pragma unroll
        for (int k = 0; k < 128; k += 8) {
            bf16x8 hv = *(const bf16x8*)(hp + k);
            bf16x8 wv = *(const bf16x8*)(wp + k);
#pragma unroll
            for (int u = 0; u < 8; ++u)
                p += bf2f((unsigned short)hv[u]) * bf2f((unsigned short)wv[u]);
        }
        red[fkq * 64 + frow] = p;
        __syncthreads();
        if (tid < 64) {
            float s = blin[fc];
#pragma unroll
            for (int u = 0; u < 8; ++u) s += red[u * 64 + tid];
            outp[((size_t)(fq * 64 + tid) * TF_SZ + tm1) * OUTDIM + fc] = s;
        }
        __syncthreads();
    };

    // ---- tail out(t) + feedback (32 blocks) ----
    auto tail_out = [&](int t, const unsigned short* hnew, int do_fb) {
        if (id < 32) {
            unsigned short* h2s = (unsigned short*)&part[0][0][0];  // [8][1024]
            const int rowbase = id * 8;
            for (int i = tid; i < 1024; i += 512) {
                const int rr = i >> 7, k8 = (i & 127) * 8;
                *(bf16x8*)&h2s[rr * 1024 + k8] =
                    *(const bf16x8*)&hnew[(size_t)(rowbase + rr) * 2048 + 1024 + k8];
            }
            __syncthreads();
            const int rl = tid >> 6, col = tid & 63;
            float acc = blin[col];
            const unsigned short* wl = Wlin + (size_t)col * HIDN;
            for (int k = 0; k < HIDN; k += 8) {
                bf16x8 hv = *(const bf16x8*)&h2s[rl * 1024 + k];
                bf16x8 wv = *(const bf16x8*)&wl[k];
#pragma unroll
                for (int u = 0; u < 8; ++u)
                    acc += bf2f((unsigned short)hv[u]) * bf2f((unsigned short)wv[u]);
            }
            outp[((size_t)(rowbase + rl) * TF_SZ + t) * OUTDIM + col] = acc;
            if (do_fb) {
                red[rl * 64 + col] = acc;
                __syncthreads();
                float x = bo2i[col];
                const unsigned short* w2 = Wo2i + (size_t)col * OUTDIM;
#pragma unroll 8
                for (int jj = 0; jj < OUTDIM; ++jj)
                    x += red[rl * 64 + jj] * bf2f(w2[jj]);
                xfut[(size_t)(rowbase + rl) * INDIM + col] = f2bf(x);
            }
        }
    };

    // ================= schedule =================
    // prologue: h1(0) from x(0), h1(-1)=0 (hh0 zeroed) -> hh1
    l1_phase(xbf, hh0, hh1);
    gbarrier(bar, ++bidx);

    // merged steady state: S_t = {fold(t-1) | L2(t) | L1(t+1)}, one barrier
    for (int t = 0; t < T_SZ - 1; ++t) {
        const unsigned short* hsrc = ((t + 1) & 1) ? hh1 : hh0;  // h1(t), h2(t-1)
        unsigned short*       hdst = (t & 1) ? hh1 : hh0;        // h2(t), h1(t+1)
        if (t >= 1) fold(t - 1, hsrc);
        l2_phase(hsrc, hdst);
        l1_phase(xbf + (size_t)(t + 1) * B_SZ * INDIM, hsrc, hdst);
        gbarrier(bar, ++bidx);
    }

    // tail: t = 255..287 (out(t) feeds x(t+1))
    for (int t = T_SZ - 1; t < TF_SZ; ++t) {
        const unsigned short* hsrc = ((t + 1) & 1) ? hh1 : hh0;
        unsigned short*       hdst = (t & 1) ? hh1 : hh0;
        if (t == T_SZ - 1) fold(t - 1, hsrc);
        l2_phase(hsrc, hdst);                       // h2(t)
        gbarrier(bar, ++bidx);
        tail_out(t, hdst, t < TF_SZ - 1);           // out(t), xfut(t+1)
        if (t < TF_SZ - 1) {
            gbarrier(bar, ++bidx);
            l1_phase(xfut, hsrc, hdst);             // h1(t+1)
            gbarrier(bar, ++bidx);
        }
    }
}

__global__ void conv_strided(const float* __restrict__ src,
                             unsigned short* __restrict__ dst,
                             int cols, int dstride, int doff, int total)
{
    const int idx = blockIdx.x * 256 + threadIdx.x;
    if (idx >= total) return;
    const int r = idx / cols, c = idx - r * cols;
    dst[(size_t)r * dstride + doff + c] = f2bf(src[idx]);
}

__global__ void conv_x(const float* __restrict__ src,
                       unsigned short* __restrict__ dst)
{
    const int idx = blockIdx.x * 256 + threadIdx.x;
    const int f = idx & 63, t = (idx >> 6) & 255, b = idx >> 14;
    dst[((size_t)t * B_SZ + b) * INDIM + f] = f2bf(src[idx]);
}

extern "C" void kernel_launch(void* const* d_in, const int* in_sizes, int n_in,
                              void* d_out, int out_size, void* d_ws, size_t ws_size,
                              hipStream_t stream)
{
    const float* input = (const float*)d_in[0];
    const float* W_ih1 = (const float*)d_in[1];
    const float* W_hh1 = (const float*)d_in[2];
    const float* b_ih1 = (const float*)d_in[3];
    const float* b_hh1 = (const float*)d_in[4];
    const float* W_ih2 = (const float*)d_in[5];
    const float* W_hh2 = (const float*)d_in[6];
    const float* b_ih2 = (const float*)d_in[7];
    const float* b_hh2 = (const float*)d_in[8];
    const float* W_lin = (const float*)d_in[9];
    const float* b_lin = (const float*)d_in[10];
    const float* W_o2i = (const float*)d_in[11];
    const float* b_o2i = (const float*)d_in[12];
    float* outp = (float*)d_out;

    char* ws = (char*)d_ws;
    unsigned short* Wcat1 = (unsigned short*)ws; ws += (size_t)4096 * 1088 * 2;
    unsigned short* Wcat2 = (unsigned short*)ws; ws += (size_t)4096 * 2048 * 2;
    unsigned short* Wlinb = (unsigned short*)ws; ws += (size_t)64 * 1024 * 2;
    unsigned short* Wo2ib = (unsigned short*)ws; ws += (size_t)64 * 64 * 2;
    unsigned short* xbf   = (unsigned short*)ws; ws += (size_t)T_SZ * B_SZ * INDIM * 2;
    unsigned short* hh0   = (unsigned short*)ws; ws += (size_t)B_SZ * 2 * HIDN * 2;
    unsigned short* hh1   = (unsigned short*)ws; ws += (size_t)B_SZ * 2 * HIDN * 2;
    unsigned short* xfut  = (unsigned short*)ws; ws += (size_t)B_SZ * INDIM * 2;
    ws = (char*)(((size_t)ws + 255) & ~(size_t)255);
    unsigned int*   bar   = (unsigned int*)ws;   ws += 256;

    conv_strided<<<(4096 * 64 + 255) / 256, 256, 0, stream>>>(W_ih1, Wcat1, 64, 1088, 0, 4096 * 64);
    conv_strided<<<(4096 * 1024 + 255) / 256, 256, 0, stream>>>(W_hh1, Wcat1, 1024, 1088, 64, 4096 * 1024);
    conv_strided<<<(4096 * 1024 + 255) / 256, 256, 0, stream>>>(W_ih2, Wcat2, 1024, 2048, 0, 4096 * 1024);
    conv_strided<<<(4096 * 1024 + 255) / 256, 256, 0, stream>>>(W_hh2, Wcat2, 1024, 2048, 1024, 4096 * 1024);
    conv_strided<<<(64 * 1024 + 255) / 256, 256, 0, stream>>>(W_lin, Wlinb, 1024, 1024, 0, 64 * 1024);
    conv_strided<<<(64 * 64 + 255) / 256, 256, 0, stream>>>(W_o2i, Wo2ib, 64, 64, 0, 64 * 64);
    conv_x<<<(T_SZ * B_SZ * INDIM) / 256, 256, 0, stream>>>(input, xbf);

    hipMemsetAsync(hh0, 0, (size_t)B_SZ * 2 * HIDN * 2, stream);
    hipMemsetAsync(hh1, 0, (size_t)B_SZ * 2 * HIDN * 2, stream);
    hipMemsetAsync(bar, 0, 256, stream);

    void* kargs[] = {
        (void*)&xbf, (void*)&xfut, (void*)&Wcat1, (void*)&Wcat2,
        (void*)&Wlinb, (void*)&Wo2ib,
        (void*)&b_ih1, (void*)&b_hh1, (void*)&b_ih2, (void*)&b_hh2,
        (void*)&b_lin, (void*)&b_o2i,
        (void*)&hh0, (void*)&hh1, (void*)&outp, (void*)&bar
    };
    hipLaunchCooperativeKernel((void*)lstm_persist, dim3(NBLK), dim3(512),
                               kargs, 0, stream);
}